// Round 6
// baseline (2921.677 us; speedup 1.0000x reference)
//
#include <hip/hip_runtime.h>
#include <math.h>

#define N_EVENTS 4096
#define TS 1024
#define NN 64
#define BLK 512          // events per sequential block
#define NBLK (N_EVENTS / BLK)

typedef int v2i __attribute__((ext_vector_type(2)));

// ---- DPP permute ----
template<int CTRL>
__device__ __forceinline__ float dppmov(float x) {
    return __int_as_float(__builtin_amdgcn_mov_dpp(__float_as_int(x), CTRL, 0xF, 0xF, true));
}
// 0xB1 quad xor1, 0x4E quad xor2, 0x141 row_half_mirror, 0x140 row_mirror

// ---- gfx950 permlane swaps (self-swap helpers for full-wave reduce) ----
#if __has_builtin(__builtin_amdgcn_permlane16_swap) && __has_builtin(__builtin_amdgcn_permlane32_swap)
__device__ __forceinline__ void sswap16(float x, float& a, float& b) {
    v2i r = __builtin_amdgcn_permlane16_swap(__float_as_int(x), __float_as_int(x), false, false);
    a = __int_as_float(r[0]); b = __int_as_float(r[1]);
}
__device__ __forceinline__ void sswap32(float x, float& a, float& b) {
    v2i r = __builtin_amdgcn_permlane32_swap(__float_as_int(x), __float_as_int(x), false, false);
    a = __int_as_float(r[0]); b = __int_as_float(r[1]);
}
#else
__device__ __forceinline__ void sswap16(float x, float& a, float& b) {
    asm("v_mov_b32 %0, %2\n\tv_mov_b32 %1, %2\n\ts_nop 1\n\tv_permlane16_swap_b32 %0, %1"
        : "=&v"(a), "=&v"(b) : "v"(x));
}
__device__ __forceinline__ void sswap32(float x, float& a, float& b) {
    asm("v_mov_b32 %0, %2\n\tv_mov_b32 %1, %2\n\ts_nop 1\n\tv_permlane32_swap_b32 %0, %1"
        : "=&v"(a), "=&v"(b) : "v"(x));
}
#endif

// ---- 64-lane all-VALU reductions, result in every lane ----
__device__ __forceinline__ float wred_add(float x) {
    x += dppmov<0xB1>(x);
    x += dppmov<0x4E>(x);
    x += dppmov<0x141>(x);
    x += dppmov<0x140>(x);
    { float a, b; sswap16(x, a, b); x = a + b; }
    { float a, b; sswap32(x, a, b); x = a + b; }
    return x;
}
__device__ __forceinline__ float wred_max(float x) {
    x = fmaxf(x, dppmov<0xB1>(x));
    x = fmaxf(x, dppmov<0x4E>(x));
    x = fmaxf(x, dppmov<0x141>(x));
    x = fmaxf(x, dppmov<0x140>(x));
    { float a, b; sswap16(x, a, b); x = fmaxf(a, b); }
    { float a, b; sswap32(x, a, b); x = fmaxf(a, b); }
    return x;
}

// ================= full-GPU prep kernels =================

__global__ void norms_kernel(const float* __restrict__ all_ts, float* __restrict__ nrm) {
    const int l = threadIdx.x & 63;
    const int wv = threadIdx.x >> 6;
    const int e = blockIdx.x * 4 + wv;
    const float4* src = (const float4*)(all_ts + (size_t)e * TS);
    float s = 0.f;
    #pragma unroll
    for (int c = 0; c < 4; ++c) {
        float4 f = src[64 * c + l];
        s = fmaf(f.x, f.x, fmaf(f.y, f.y, fmaf(f.z, f.z, fmaf(f.w, f.w, s))));
    }
    const float tsn = sqrtf(wred_add(s));
    if (l == 0) nrm[e] = tsn;
}

__global__ void wnorm0_kernel(const float* __restrict__ W, const float* __restrict__ ch,
                              float* __restrict__ wn_g, float* __restrict__ hist_g) {
    const int l = threadIdx.x & 63;
    const int wv = threadIdx.x >> 6;
    const int r = blockIdx.x * 4 + wv;
    const float4* row = (const float4*)(W + (size_t)r * TS);
    float s = 0.f;
    #pragma unroll
    for (int c = 0; c < 4; ++c) {
        float4 f = row[64 * c + l];
        s = fmaf(f.x, f.x, fmaf(f.y, f.y, fmaf(f.z, f.z, fmaf(f.w, f.w, s))));
    }
    const float tot = wred_add(s);
    if (l == 0) wn_g[r] = sqrtf(tot);
    if (blockIdx.x == 0 && threadIdx.x < NN) hist_g[threadIdx.x] = ch[threadIdx.x];
}

// Gram diagonal-block tiles: Gt[b][i][j] = ts_{b*512+i} . ts_{b*512+j}, j>=i tiles
__global__ void gtile_kernel(const float* __restrict__ ts, float* __restrict__ Gt) {
    const int tj = blockIdx.x, ti = blockIdx.y, b = blockIdx.z;
    if (tj < ti) return;
    __shared__ float As[32][36];
    __shared__ float Bs[32][36];
    const float* base = ts + (size_t)b * BLK * TS;
    const int tid = threadIdx.x;
    const int ty = tid >> 4, tx = tid & 15;
    const int lr = tid >> 3, lc = (tid & 7) << 2;
    float a00 = 0, a01 = 0, a10 = 0, a11 = 0;
    for (int k0 = 0; k0 < TS; k0 += 32) {
        float4 av = *(const float4*)(base + (size_t)(ti * 32 + lr) * TS + k0 + lc);
        float4 bv = *(const float4*)(base + (size_t)(tj * 32 + lr) * TS + k0 + lc);
        __syncthreads();
        *(float4*)&As[lr][lc] = av;
        *(float4*)&Bs[lr][lc] = bv;
        __syncthreads();
        #pragma unroll
        for (int kk = 0; kk < 32; kk += 4) {
            const float4 x0 = *(const float4*)&As[2 * ty][kk];
            const float4 x1 = *(const float4*)&As[2 * ty + 1][kk];
            const float4 y0 = *(const float4*)&Bs[2 * tx][kk];
            const float4 y1 = *(const float4*)&Bs[2 * tx + 1][kk];
            a00 = fmaf(x0.x, y0.x, fmaf(x0.y, y0.y, fmaf(x0.z, y0.z, fmaf(x0.w, y0.w, a00))));
            a01 = fmaf(x0.x, y1.x, fmaf(x0.y, y1.y, fmaf(x0.z, y1.z, fmaf(x0.w, y1.w, a01))));
            a10 = fmaf(x1.x, y0.x, fmaf(x1.y, y0.y, fmaf(x1.z, y0.z, fmaf(x1.w, y0.w, a10))));
            a11 = fmaf(x1.x, y1.x, fmaf(x1.y, y1.y, fmaf(x1.z, y1.z, fmaf(x1.w, y1.w, a11))));
        }
    }
    float* g = Gt + (size_t)b * BLK * BLK;
    const int i0 = ti * 32 + 2 * ty, j0 = tj * 32 + 2 * tx;
    g[(size_t)i0 * BLK + j0]           = a00;
    g[(size_t)i0 * BLK + j0 + 1]       = a01;
    g[(size_t)(i0 + 1) * BLK + j0]     = a10;
    g[(size_t)(i0 + 1) * BLK + j0 + 1] = a11;
}

// D refresh for one block; stores TRANSPOSED + XOR-SWIZZLED:
//   D_g[f*64 + (n ^ (f&31))] = W_cur[n] . ts_f
__global__ void dgemm_kernel(const float* __restrict__ Wc, const float* __restrict__ tsb,
                             float* __restrict__ D_g) {
    const int tj = blockIdx.x, ti = blockIdx.y;
    __shared__ float As[32][36];
    __shared__ float Bs[32][36];
    const int tid = threadIdx.x;
    const int ty = tid >> 4, tx = tid & 15;
    const int lr = tid >> 3, lc = (tid & 7) << 2;
    float a00 = 0, a01 = 0, a10 = 0, a11 = 0;
    for (int k0 = 0; k0 < TS; k0 += 32) {
        float4 av = *(const float4*)(Wc + (size_t)(ti * 32 + lr) * TS + k0 + lc);
        float4 bv = *(const float4*)(tsb + (size_t)(tj * 32 + lr) * TS + k0 + lc);
        __syncthreads();
        *(float4*)&As[lr][lc] = av;
        *(float4*)&Bs[lr][lc] = bv;
        __syncthreads();
        #pragma unroll
        for (int kk = 0; kk < 32; kk += 4) {
            const float4 x0 = *(const float4*)&As[2 * ty][kk];
            const float4 x1 = *(const float4*)&As[2 * ty + 1][kk];
            const float4 y0 = *(const float4*)&Bs[2 * tx][kk];
            const float4 y1 = *(const float4*)&Bs[2 * tx + 1][kk];
            a00 = fmaf(x0.x, y0.x, fmaf(x0.y, y0.y, fmaf(x0.z, y0.z, fmaf(x0.w, y0.w, a00))));
            a01 = fmaf(x0.x, y1.x, fmaf(x0.y, y1.y, fmaf(x0.z, y1.z, fmaf(x0.w, y1.w, a01))));
            a10 = fmaf(x1.x, y0.x, fmaf(x1.y, y0.y, fmaf(x1.z, y0.z, fmaf(x1.w, y0.w, a10))));
            a11 = fmaf(x1.x, y1.x, fmaf(x1.y, y1.y, fmaf(x1.z, y1.z, fmaf(x1.w, y1.w, a11))));
        }
    }
    const int n0 = ti * 32 + 2 * ty, f0 = tj * 32 + 2 * tx;
    D_g[(size_t)f0 * 64       + ((n0)     ^ (f0 & 31))]       = a00;
    D_g[(size_t)(f0 + 1) * 64 + ((n0)     ^ ((f0 + 1) & 31))] = a01;
    D_g[(size_t)f0 * 64       + ((n0 + 1) ^ (f0 & 31))]       = a10;
    D_g[(size_t)(f0 + 1) * 64 + ((n0 + 1) ^ ((f0 + 1) & 31))] = a11;
}

// W rebuild: replay block-b's (winner, coef) log
__global__ void rebuild_kernel(float* __restrict__ Wc, const float* __restrict__ ts,
                               const int* __restrict__ win, const float* __restrict__ coef_g,
                               const float* __restrict__ nrm, int b) {
    const int n = blockIdx.x;
    const int d = blockIdx.y * 256 + threadIdx.x;
    float wv = Wc[(size_t)n * TS + d];
    const int e0 = b * BLK;
    #pragma unroll 1
    for (int i = 0; i < BLK; ++i) {
        if (win[e0 + i] == n) {
            const float rtn = __builtin_amdgcn_rcpf(nrm[e0 + i]);
            const float tn = ts[(size_t)(e0 + i) * TS + d] * rtn;
            const float c = coef_g[e0 + i];
            wv = fmaf(c, tn - wv, wv);
        }
    }
    Wc[(size_t)n * TS + d] = wv;
}

// ================= single-wave sequential core =================
// LDS layout: D[n][f] stored at word f*64 + (n ^ (f&31)); dump slots after.
#define DUMPB 131072u

// One event. GC = this parity's G row regs; TSC/SDC = this parity's tsn / Gram-diag.
#define STEP(I, GC, TSC, SDC)                                                   \
    {                                                                           \
        const float tsn = TSC;                                                  \
        const float sd  = SDC;                                                  \
        TSC = nrm[e0 + (I) + 2];                 /* prefetch, same parity */    \
        SDC = Gt_b[513 * ((I) + 2) + 1];                                        \
        const float rtn  = __builtin_amdgcn_rcpf(tsn);                          \
        const float beta = dv * __builtin_amdgcn_rcpf(tsn * wnl);               \
        const float score = gain * beta;                                        \
        const float coefl = alpha * beta;                                       \
        /* prefetch next D column BEFORE this step's update writes */           \
        const float dv_pre = Dl[((((I) + 1) & 511) << 6) + (l ^ (((I) + 1) & 31))]; \
        const float smax = wred_max(score);                                     \
        const unsigned long long mk = __ballot(score == smax);                  \
        const int ns = (int)(__ffsll(mk) - 1);                                  \
        const float coef = __shfl(coefl, ns, 64);                               \
        const float bw   = __shfl(beta,  ns, 64);                               \
        if (l == 0) { out[e0 + (I)] = ns; coef_g[e0 + (I)] = coef; }            \
        /* rank-1 update of row ns, cols f = I+1+l+64k (f>=512 -> dump) */      \
        {                                                                       \
            const unsigned f0u = (unsigned)((I) + 1 + l);                       \
            const unsigned fb = (f0u << 8) + (((unsigned)ns ^ (f0u & 31u)) << 2); \
            const unsigned dmp = DUMPB + ((unsigned)l << 2);                    \
            _Pragma("unroll")                                                   \
            for (int k = 0; k < 8; ++k) {                                       \
                unsigned a = fb + 16384u * (unsigned)k;                         \
                a = a < dmp ? a : dmp;                                          \
                float* p = (float*)((char*)Dl + a);                             \
                const float dvv = *p;                                           \
                *p = fmaf(coef, rtn * GC[k] - dvv, dvv);                        \
            }                                                                   \
        }                                                                       \
        /* refill this parity's G bank with row I+2 */                          \
        {                                                                       \
            const float* gr = Gt_b + 512 * ((I) + 2) + ((I) + 3 + l);           \
            _Pragma("unroll")                                                   \
            for (int k = 0; k < 8; ++k) GC[k] = gr[64 * k];                     \
        }                                                                       \
        /* in-register fixup of the prefetched column (winner lane only) */     \
        const float fx = fmaf(coef, rtn * sd - dv_pre, dv_pre);                 \
        dv = (l == ns) ? fx : dv_pre;                                           \
        const float om = 1.0f - coef;                                           \
        const float wn_new = sqrtf(om * om * wnl * wnl                          \
                                   + 2.0f * coef * om * bw * wnl + coef * coef); \
        if (l == ns) { wnl = wn_new; hll += 1.0f; }                             \
        hs += 1.0f;                                                             \
        gain  = __expf(0.25f - 16.0f * hll * __builtin_amdgcn_rcpf(hs));        \
        alpha = 0.01f * __builtin_amdgcn_rcpf(fmaf(hll, 1.0f / 20000.0f, 1.0f)); \
    }

__launch_bounds__(64, 1)
__global__ void seq_kernel(const float* __restrict__ D_g, const float* __restrict__ Gt_b,
                           const float* __restrict__ nrm, float* __restrict__ wn_g,
                           float* __restrict__ hist_g, int* __restrict__ out,
                           float* __restrict__ coef_g, int b)
{
    __shared__ float Dl[NN * BLK + 64];   // 128 KB + dump
    const int l = threadIdx.x;            // 64 threads = 1 wave; lane l = neuron l

    // fill D (already transposed+swizzled by dgemm): linear float4 copy
    {
        const float4* Dg4 = (const float4*)D_g;
        float4* Dl4 = (float4*)Dl;
        #pragma unroll 8
        for (int c = 0; c < 128; ++c) Dl4[c * 64 + l] = Dg4[c * 64 + l];
    }

    const int e0 = b * BLK;
    float wnl = wn_g[l];
    float hll = hist_g[l];
    float hs  = 64.0f + (float)e0;
    float gain  = __expf(0.25f - 16.0f * hll * __builtin_amdgcn_rcpf(hs));
    float alpha = 0.01f * __builtin_amdgcn_rcpf(fmaf(hll, 1.0f / 20000.0f, 1.0f));

    // G rows 0 and 1 into the two parity banks
    float gA[8], gB[8];
    {
        const float* gr = Gt_b + (1 + l);
        #pragma unroll
        for (int k = 0; k < 8; ++k) gA[k] = gr[64 * k];
    }
    {
        const float* gr = Gt_b + 512 + (2 + l);
        #pragma unroll
        for (int k = 0; k < 8; ++k) gB[k] = gr[64 * k];
    }
    float tsA = nrm[e0], tsB = nrm[e0 + 1];
    float sdA = Gt_b[1], sdB = Gt_b[513 + 1];
    float dv = Dl[l];    // D[l][0]

    #pragma unroll 1
    for (int i = 0; i < BLK; i += 2) {
        STEP(i,     gA, tsA, sdA);
        STEP(i + 1, gB, tsB, sdB);
    }

    wn_g[l] = wnl;
    hist_g[l] = hll;
}

// ================= launch =================
// ws layout (floats). GT first so any tail over-reads land in our own arrays.
#define GT_OFF    0                          // 8 * 512 * 512 = 2097152
#define NRM_OFF   2097152                    // 4096
#define WN_OFF    2101248                    // 64
#define HIST_OFF  2101312                    // 64
#define COEF_OFF  2101376                    // 4096
#define D_OFF     2105472                    // 32768
#define W_OFF     2138240                    // 65536  -> total 2203776 floats (8.8 MB)

extern "C" void kernel_launch(void* const* d_in, const int* in_sizes, int n_in,
                              void* d_out, int out_size, void* d_ws, size_t ws_size,
                              hipStream_t stream) {
    const float* all_ts   = (const float*)d_in[0];
    const float* W        = (const float*)d_in[1];
    const float* cumhisto = (const float*)d_in[2];
    int* out = (int*)d_out;
    float* ws = (float*)d_ws;

    float* Gt     = ws + GT_OFF;
    float* nrm    = ws + NRM_OFF;
    float* wn_g   = ws + WN_OFF;
    float* hist_g = ws + HIST_OFF;
    float* coef_g = ws + COEF_OFF;
    float* D_g    = ws + D_OFF;
    float* W_cur  = ws + W_OFF;

    hipMemcpyAsync(W_cur, W, (size_t)NN * TS * sizeof(float),
                   hipMemcpyDeviceToDevice, stream);
    norms_kernel<<<N_EVENTS / 4, 256, 0, stream>>>(all_ts, nrm);
    wnorm0_kernel<<<16, 256, 0, stream>>>(W, cumhisto, wn_g, hist_g);
    gtile_kernel<<<dim3(16, 16, NBLK), 256, 0, stream>>>(all_ts, Gt);

    for (int b = 0; b < NBLK; ++b) {
        dgemm_kernel<<<dim3(16, 2), 256, 0, stream>>>(
            W_cur, all_ts + (size_t)b * BLK * TS, D_g);
        seq_kernel<<<1, 64, 0, stream>>>(
            D_g, Gt + (size_t)b * BLK * BLK, nrm, wn_g, hist_g, out, coef_g, b);
        if (b < NBLK - 1)
            rebuild_kernel<<<dim3(NN, 4), 256, 0, stream>>>(
                W_cur, all_ts, out, coef_g, nrm, b);
    }
}